// Round 1
// baseline (123.820 us; speedup 1.0000x reference)
//
#include <hip/hip_runtime.h>
#include <math.h>

// Problem constants
#define Nn   8192
#define DXc  64
#define DZc  128
#define DYc  16
#define Hc   512
#define KC   (Hc + DZc + DYc)   // 656 = concat K dim: [s | z_pred | y]
#define NT   16                 // samples per block
#define SROW 660                // padded LDS row stride (floats); 660*4 B is 16B-aligned

__device__ __forceinline__ float fast_tanh(float x) {
    // tanh(x) = 1 - 2/(exp(2x)+1); exact limits at +/-inf, ~1e-7 rel err
    float e = __expf(2.0f * x);
    return 1.0f - 2.0f / (e + 1.0f);
}

// Prep: tx = tanh(x_label) (scalar-load-friendly copy), Wc = [W2; -A^T; -B^T]
__global__ void prep_kernel(const float* __restrict__ x_label,
                            const float* __restrict__ W2,
                            const float* __restrict__ A,
                            const float* __restrict__ Bm,
                            float* __restrict__ tx,
                            float* __restrict__ Wc) {
    int idx = blockIdx.x * 256 + threadIdx.x;
    if (idx < Nn * DXc) tx[idx] = fast_tanh(x_label[idx]);
    if (idx < KC * DZc) {
        int j = idx >> 7;      // row in Wc
        int z = idx & 127;     // col
        float w;
        if (j < Hc)            w =  W2[j * DZc + z];
        else if (j < Hc + DZc) w = -A[z * DZc + (j - Hc)];
        else                   w = -Bm[z * DYc + (j - Hc - DZc)];
        Wc[idx] = w;
    }
}

#define FMA4(accv, sv, a, b, c, d) \
    accv = fmaf((sv).x, (a), accv); accv = fmaf((sv).y, (b), accv); \
    accv = fmaf((sv).z, (c), accv); accv = fmaf((sv).w, (d), accv);

__global__ __launch_bounds__(256, 2)
void pde_kernel(const float* __restrict__ z_pred,
                const float* __restrict__ x_label,
                const float* __restrict__ y_label,
                const float* __restrict__ W1,
                const float* __restrict__ b1,
                const float* __restrict__ tx,
                const float* __restrict__ Wc,
                float* __restrict__ out) {
    __shared__ float sld[NT * SROW];   // [s | z | y] tile, 16 x 660
    __shared__ float red[128 * 16];    // jg cross-reduction buffer
    __shared__ float tot[NT];          // per-sample sum of squares

    const int tid = threadIdx.x;
    const int n0  = blockIdx.x * NT;

    // ---- stage z_pred, y_label into concat columns [512,656) ----
    for (int k = tid; k < NT * DZc; k += 256) {
        int n = k >> 7, c = k & 127;
        sld[n * SROW + Hc + c] = z_pred[(size_t)(n0 + n) * DZc + c];
    }
    {
        int n = tid >> 4, c = tid & 15;          // exactly 256 = NT*DYc elems
        sld[n * SROW + Hc + DZc + c] = y_label[(n0 + n) * DYc + c];
    }

    // ---- phase 1: h = x@W1+b1, u = tanh(x)@W1 for j0=tid, j1=tid+256 ----
    const int j0 = tid, j1 = tid + 256;
    float h0[NT], u0[NT], h1[NT], u1[NT];
    const float bj0 = b1[j0], bj1 = b1[j1];
#pragma unroll
    for (int n = 0; n < NT; n++) { h0[n] = bj0; u0[n] = 0.f; h1[n] = bj1; u1[n] = 0.f; }

    const float4* xr = (const float4*)(x_label + (size_t)n0 * DXc);
    const float4* tr = (const float4*)(tx      + (size_t)n0 * DXc);

    for (int dc = 0; dc < DXc / 4; dc++) {
        const float* wp = W1 + (size_t)(4 * dc) * Hc + j0;
        float wa0 = wp[0],    wa1 = wp[Hc],     wa2 = wp[2*Hc],     wa3 = wp[3*Hc];
        float wb0 = wp[256],  wb1 = wp[Hc+256], wb2 = wp[2*Hc+256], wb3 = wp[3*Hc+256];
#pragma unroll
        for (int n = 0; n < NT; n++) {
            float4 xv = xr[n * (DXc/4) + dc];   // uniform address -> scalar load
            float4 tv = tr[n * (DXc/4) + dc];
            FMA4(h0[n], xv, wa0, wa1, wa2, wa3);
            FMA4(u0[n], tv, wa0, wa1, wa2, wa3);
            FMA4(h1[n], xv, wb0, wb1, wb2, wb3);
            FMA4(u1[n], tv, wb0, wb1, wb2, wb3);
        }
    }

    // s = (1 - tanh(h)^2) * u  -> LDS
#pragma unroll
    for (int n = 0; n < NT; n++) {
        float t0 = fast_tanh(h0[n]);
        float t1 = fast_tanh(h1[n]);
        sld[n * SROW + j0] = (1.f - t0 * t0) * u0[n];
        sld[n * SROW + j1] = (1.f - t1 * t1) * u1[n];
    }
    __syncthreads();

    // ---- phase 2: pde[n,z] = sum_j sld[n][j] * Wc[j][z] ----
    const int zg = tid & 31;
    const int ng = (tid >> 5) & 3;
    const int jg = tid >> 7;        // j-range split in half across thread halves
    const int z0 = zg * 4;
    const int nb = ng * 4;
    float acc[4][4];
#pragma unroll
    for (int n = 0; n < 4; n++)
#pragma unroll
        for (int zz = 0; zz < 4; zz++) acc[n][zz] = 0.f;

    for (int jc = 0; jc < (KC / 2) / 4; jc++) {   // 82 chunks of 4 j
        const int j = jg * (KC / 2) + jc * 4;
        const float4 w0 = *(const float4*)(Wc + (size_t)(j + 0) * DZc + z0);
        const float4 w1 = *(const float4*)(Wc + (size_t)(j + 1) * DZc + z0);
        const float4 w2 = *(const float4*)(Wc + (size_t)(j + 2) * DZc + z0);
        const float4 w3 = *(const float4*)(Wc + (size_t)(j + 3) * DZc + z0);
#pragma unroll
        for (int n = 0; n < 4; n++) {
            const float4 sv = *(const float4*)(sld + (nb + n) * SROW + j);
            FMA4(acc[n][0], sv, w0.x, w1.x, w2.x, w3.x);
            FMA4(acc[n][1], sv, w0.y, w1.y, w2.y, w3.y);
            FMA4(acc[n][2], sv, w0.z, w1.z, w2.z, w3.z);
            FMA4(acc[n][3], sv, w0.w, w1.w, w2.w, w3.w);
        }
    }

    // ---- phase 3: combine j-halves, row norms, mean ----
    if (jg == 1) {
#pragma unroll
        for (int n = 0; n < 4; n++)
#pragma unroll
            for (int zz = 0; zz < 4; zz++)
                red[(tid - 128) * 16 + n * 4 + zz] = acc[n][zz];
    }
    __syncthreads();

    if (jg == 0) {
        float sq[4];
#pragma unroll
        for (int n = 0; n < 4; n++) {
            sq[n] = 0.f;
#pragma unroll
            for (int zz = 0; zz < 4; zz++) {
                float v = acc[n][zz] + red[tid * 16 + n * 4 + zz];
                sq[n] = fmaf(v, v, sq[n]);
            }
        }
        // reduce across the 32 zg lanes (masks <=16 stay within 32-lane halves)
#pragma unroll
        for (int n = 0; n < 4; n++) {
            sq[n] += __shfl_xor(sq[n], 1);
            sq[n] += __shfl_xor(sq[n], 2);
            sq[n] += __shfl_xor(sq[n], 4);
            sq[n] += __shfl_xor(sq[n], 8);
            sq[n] += __shfl_xor(sq[n], 16);
        }
        if (zg == 0) {
#pragma unroll
            for (int n = 0; n < 4; n++) tot[nb + n] = sq[n];
        }
    }
    __syncthreads();

    if (tid == 0) {
        float s = 0.f;
#pragma unroll
        for (int n = 0; n < NT; n++) s += sqrtf(tot[n]);
        atomicAdd(out, s * (1.0f / (float)Nn));
    }
}

extern "C" void kernel_launch(void* const* d_in, const int* in_sizes, int n_in,
                              void* d_out, int out_size, void* d_ws, size_t ws_size,
                              hipStream_t stream) {
    const float* z_pred  = (const float*)d_in[0];
    const float* x_label = (const float*)d_in[1];
    const float* y_label = (const float*)d_in[2];
    const float* W1      = (const float*)d_in[3];
    const float* b1      = (const float*)d_in[4];
    const float* W2      = (const float*)d_in[5];
    // d_in[6] = b2: cancels in the Jacobian-vector product, unused
    const float* A       = (const float*)d_in[7];
    const float* Bm      = (const float*)d_in[8];
    float* out = (float*)d_out;

    float* Wc = (float*)d_ws;                 // 656*128 floats = 336 KB
    float* tx = (float*)d_ws + (size_t)KC * DZc;  // 8192*64 floats = 2 MB

    hipMemsetAsync(d_out, 0, sizeof(float), stream);
    prep_kernel<<<(Nn * DXc) / 256, 256, 0, stream>>>(x_label, W2, A, Bm, tx, Wc);
    pde_kernel<<<Nn / NT, 256, 0, stream>>>(z_pred, x_label, y_label, W1, b1, tx, Wc, out);
}

// Round 2
// 87.060 us; speedup vs baseline: 1.4222x; 1.4222x over previous
//
#include <hip/hip_runtime.h>
#include <math.h>

// Problem constants
#define Nn   8192
#define DXc  64
#define DZc  128
#define DYc  16
#define Hc   512
#define KCp  672    // padded concat K: 512 (H) + 128 (z) + 16 (y) + 16 zeros
#define SSTR 72     // LDS S-tile row stride (bf16 elems) = 144 B: 16B-aligned, conflict-light

typedef short bf16x8 __attribute__((ext_vector_type(8)));   // 8 bf16 = 4 VGPRs
typedef float f32x4  __attribute__((ext_vector_type(4)));

__device__ __forceinline__ float fast_tanh(float x) {
    // exact limits at +/-inf, ~1e-7 rel err
    float e = __expf(2.0f * x);
    return 1.0f - 2.0f / (e + 1.0f);
}
__device__ __forceinline__ short f2bf(float f) {            // fp32 -> bf16 RNE
    unsigned u = __float_as_uint(f);
    return (short)((u + 0x7FFFu + ((u >> 16) & 1u)) >> 16);
}

// ---- prep: W1T[j][k] = bf16(W1[k][j]); WcT[z][k] = bf16([W2; -A^T; -B^T]^T), K-padded ----
__global__ void prep_kernel(const float* __restrict__ W1,
                            const float* __restrict__ W2,
                            const float* __restrict__ A,
                            const float* __restrict__ Bm,
                            short* __restrict__ W1T,
                            short* __restrict__ WcT) {
    int idx = blockIdx.x * 256 + threadIdx.x;
    if (idx < Hc * DXc) {
        int j = idx >> 6, k = idx & 63;
        W1T[idx] = f2bf(W1[k * Hc + j]);
    }
    int i2 = idx - Hc * DXc;
    if (i2 >= 0 && i2 < DZc * KCp) {
        int z = i2 / KCp, k = i2 - z * KCp;
        float v = 0.f;
        if (k < Hc)                  v =  W2[k * DZc + z];
        else if (k < Hc + DZc)       v = -A[z * DZc + (k - Hc)];
        else if (k < Hc + DZc + DYc) v = -Bm[z * DYc + (k - Hc - DZc)];
        WcT[i2] = f2bf(v);
    }
}

#define MFMA16(a, b, c) __builtin_amdgcn_mfma_f32_16x16x32_bf16((a), (b), (c), 0, 0, 0)

// ---- main: 16 samples/block, 4 waves split K = [8 S-chunks | 2 z-chunks | 1 y-chunk] ----
__global__ __launch_bounds__(256, 2)
void pde_main(const float* __restrict__ z_pred,
              const float* __restrict__ x_label,
              const float* __restrict__ y_label,
              const float* __restrict__ b1,
              const short* __restrict__ W1T,
              const short* __restrict__ WcT,
              float* __restrict__ partial) {
    __shared__ __align__(16) short sS[4][16 * SSTR];  // per-wave S chunk (16 x 64 bf16)
    __shared__ float Pred[4][16][DZc];                // per-wave partial P
    __shared__ float rsum[16];
    __shared__ float norms[16];

    const int tid  = threadIdx.x;
    const int w    = tid >> 6;
    const int lane = tid & 63;
    const int n16  = lane & 15;       // A-frag row m / C-frag col
    const int q    = lane >> 4;       // quad
    const int n0   = blockIdx.x * 16;

    if (tid < 16) rsum[tid] = 0.f;

    f32x4 accP[8];
#pragma unroll
    for (int zt = 0; zt < 8; zt++) accP[zt] = (f32x4){0.f, 0.f, 0.f, 0.f};

    // --- x / tanh(x) A-fragments: A[m=n16][k=q*8+i], K=64 -> 2 k-chunks ---
    const float4* xr4 = (const float4*)(x_label + (size_t)(n0 + n16) * DXc + q * 8);
    float4 x0 = xr4[0], x1 = xr4[1];          // k = q*8 .. q*8+7
    float4 x2 = xr4[8], x3 = xr4[9];          // k = 32+q*8 ..
    bf16x8 ax0, ax1, at0, at1;
    {
        const float* xa = (const float*)&x0;  // x0,x1 contiguous? not guaranteed -> elementwise
        float v[16] = {x0.x,x0.y,x0.z,x0.w, x1.x,x1.y,x1.z,x1.w,
                       x2.x,x2.y,x2.z,x2.w, x3.x,x3.y,x3.z,x3.w};
        (void)xa;
#pragma unroll
        for (int i = 0; i < 8; i++) {
            ax0[i] = f2bf(v[i]);                ax1[i] = f2bf(v[8 + i]);
            at0[i] = f2bf(fast_tanh(v[i]));     at1[i] = f2bf(fast_tanh(v[8 + i]));
        }
    }

    short* sw = &sS[w][0];

    // --- S-chunks: this wave owns j-chunks w*64 and (w+4)*64 ---
#pragma unroll
    for (int cc = 0; cc < 2; cc++) {
        const int jbase = (w + cc * 4) * 64;
        // phase B: h = x@W1 (+b1), u = tanh(x)@W1 ; s = (1-tanh(h)^2)*u -> LDS
#pragma unroll
        for (int t = 0; t < 4; t++) {
            const int jt = jbase + t * 16;
            const short* bp = W1T + (size_t)(jt + n16) * DXc + q * 8;  // B[k][n]=W1T[n-row][k]
            bf16x8 bw0 = *(const bf16x8*)bp;
            bf16x8 bw1 = *(const bf16x8*)(bp + 32);
            f32x4 h = (f32x4){0.f, 0.f, 0.f, 0.f};
            f32x4 u = (f32x4){0.f, 0.f, 0.f, 0.f};
            h = MFMA16(ax0, bw0, h);  h = MFMA16(ax1, bw1, h);
            u = MFMA16(at0, bw0, u);  u = MFMA16(at1, bw1, u);
            const float bj = b1[jt + n16];       // C-layout: col = n16
#pragma unroll
            for (int reg = 0; reg < 4; reg++) {  // C row = q*4+reg
                float tv = fast_tanh(h[reg] + bj);
                float s  = (1.f - tv * tv) * u[reg];
                sw[(q * 4 + reg) * SSTR + t * 16 + n16] = f2bf(s);
            }
        }
        // phase C: accP += S_chunk @ Wc[jbase:jbase+64, :]
        bf16x8 sa0 = *(const bf16x8*)(sw + n16 * SSTR + q * 8);
        bf16x8 sa1 = *(const bf16x8*)(sw + n16 * SSTR + 32 + q * 8);
#pragma unroll
        for (int zt = 0; zt < 8; zt++) {
            const short* wp = WcT + (size_t)(zt * 16 + n16) * KCp + jbase + q * 8;
            bf16x8 w0 = *(const bf16x8*)wp;
            bf16x8 w1 = *(const bf16x8*)(wp + 32);
            accP[zt] = MFMA16(sa0, w0, accP[zt]);
            accP[zt] = MFMA16(sa1, w1, accP[zt]);
        }
    }

    // --- correction chunks: waves 0,1 -> z@(-A^T); wave 2 -> y@(-B^T) ---
    if (w < 2) {
        const int kz = w * 64;
        const float4* zr4 = (const float4*)(z_pred + (size_t)(n0 + n16) * DZc + kz + q * 8);
        float4 z0 = zr4[0], z1 = zr4[1], z2 = zr4[8], z3 = zr4[9];
        float v[16] = {z0.x,z0.y,z0.z,z0.w, z1.x,z1.y,z1.z,z1.w,
                       z2.x,z2.y,z2.z,z2.w, z3.x,z3.y,z3.z,z3.w};
        bf16x8 az0, az1;
#pragma unroll
        for (int i = 0; i < 8; i++) { az0[i] = f2bf(v[i]); az1[i] = f2bf(v[8 + i]); }
        const int kb = Hc + kz;
#pragma unroll
        for (int zt = 0; zt < 8; zt++) {
            const short* wp = WcT + (size_t)(zt * 16 + n16) * KCp + kb + q * 8;
            bf16x8 w0 = *(const bf16x8*)wp;
            bf16x8 w1 = *(const bf16x8*)(wp + 32);
            accP[zt] = MFMA16(az0, w0, accP[zt]);
            accP[zt] = MFMA16(az1, w1, accP[zt]);
        }
    } else if (w == 2) {
        bf16x8 ay = (bf16x8){0,0,0,0,0,0,0,0};
        if (q < 2) {   // k = q*8+i < 16 are real y cols; k>=16 zero (WcT rows 656.. are 0 too)
            const float4* yr4 = (const float4*)(y_label + (size_t)(n0 + n16) * DYc + q * 8);
            float4 y0 = yr4[0], y1 = yr4[1];
            float v[8] = {y0.x,y0.y,y0.z,y0.w, y1.x,y1.y,y1.z,y1.w};
#pragma unroll
            for (int i = 0; i < 8; i++) ay[i] = f2bf(v[i]);
        }
        const int kb = Hc + DZc;  // 640
#pragma unroll
        for (int zt = 0; zt < 8; zt++) {
            const short* wp = WcT + (size_t)(zt * 16 + n16) * KCp + kb + q * 8;
            bf16x8 w0 = *(const bf16x8*)wp;
            accP[zt] = MFMA16(ay, w0, accP[zt]);
        }
    }

    // --- cross-wave reduce + row norms ---
#pragma unroll
    for (int zt = 0; zt < 8; zt++)
#pragma unroll
        for (int reg = 0; reg < 4; reg++)
            Pred[w][q * 4 + reg][zt * 16 + n16] = accP[zt][reg];
    __syncthreads();

    {
        const int r = tid & 15, seg = tid >> 4;   // 16 segs x 8 cols
        float ss = 0.f;
#pragma unroll
        for (int c8 = 0; c8 < 8; c8++) {
            int c = seg * 8 + c8;
            float v = Pred[0][r][c] + Pred[1][r][c] + Pred[2][r][c] + Pred[3][r][c];
            ss = fmaf(v, v, ss);
        }
        atomicAdd(&rsum[r], ss);
    }
    __syncthreads();
    if (tid < 16) norms[tid] = sqrtf(rsum[tid]);
    __syncthreads();
    if (tid == 0) {
        float s = 0.f;
#pragma unroll
        for (int i = 0; i < 16; i++) s += norms[i];
        partial[blockIdx.x] = s;
    }
}

// ---- final: 512 block partials -> mean ----
__global__ void reduce_kernel(const float* __restrict__ partial, float* __restrict__ out) {
    __shared__ float s4[4];
    int tid = threadIdx.x;
    float v = partial[tid] + partial[tid + 256];
#pragma unroll
    for (int off = 32; off >= 1; off >>= 1) v += __shfl_down(v, off);
    if ((tid & 63) == 0) s4[tid >> 6] = v;
    __syncthreads();
    if (tid == 0) out[0] = (s4[0] + s4[1] + s4[2] + s4[3]) * (1.0f / (float)Nn);
}

extern "C" void kernel_launch(void* const* d_in, const int* in_sizes, int n_in,
                              void* d_out, int out_size, void* d_ws, size_t ws_size,
                              hipStream_t stream) {
    const float* z_pred  = (const float*)d_in[0];
    const float* x_label = (const float*)d_in[1];
    const float* y_label = (const float*)d_in[2];
    const float* W1      = (const float*)d_in[3];
    const float* b1      = (const float*)d_in[4];
    const float* W2      = (const float*)d_in[5];
    // d_in[6] = b2: cancels in the Jacobian-vector product
    const float* A       = (const float*)d_in[7];
    const float* Bm      = (const float*)d_in[8];

    short* W1T = (short*)d_ws;                       // 512*64 bf16  = 64 KB
    short* WcT = W1T + Hc * DXc;                     // 128*672 bf16 = 168 KB
    float* partial = (float*)(WcT + DZc * KCp);      // 512 floats

    const int prep_elems = Hc * DXc + DZc * KCp;     // 118784
    prep_kernel<<<(prep_elems + 255) / 256, 256, 0, stream>>>(W1, W2, A, Bm, W1T, WcT);
    pde_main<<<Nn / 16, 256, 0, stream>>>(z_pred, x_label, y_label, b1, W1T, WcT, partial);
    reduce_kernel<<<1, 256, 0, stream>>>(partial, (float*)d_out);
}